// Round 8
// baseline (116.968 us; speedup 1.0000x reference)
//
#include <hip/hip_runtime.h>
#include <stdint.h>

#define NFEAT 16
#define NCOLS 969            // 1 bias + 16 deg1 + 136 deg2 + 816 deg3
#define NROWS 65536
#define CHUNK 323            // 969 = 3 * 323
#define LSTRIDE 324          // chunk-local LDS row stride (dwords); %32=4 -> 4-way write alias (cheap)
#define PASS_ROWS 32

typedef float floatx4 __attribute__((ext_vector_type(4)));

// ---------------------------------------------------------------------------
// Static compute of global cols [RBASE, REND) of one row into chunk-local LDS
// (base CHBASE). All 969 columns emitted in sklearn/jax reference order
// (verified absmax 0.0 in R1/R3-R7); out-of-range emits are compile-time dead.
// 32 active lanes per body (round-7 lesson: never fewer).
// (RBASE - CHBASE) % 4 == 0 keeps the b128 LDS writes 16B-aligned.
// ---------------------------------------------------------------------------
template<int CHBASE, int RBASE, int REND>
__device__ __forceinline__ void compute_range(const float* xr, float* ldsrow) {
    float buf[4];
    int col = 0;
#define EMIT(P) do { \
    if (col >= RBASE && col < REND) { \
        buf[(col - RBASE) & 3] = (P); \
        if (((col - RBASE) & 3) == 3) { \
            floatx4 p; p[0] = buf[0]; p[1] = buf[1]; p[2] = buf[2]; p[3] = buf[3]; \
            *(floatx4*)&ldsrow[col - 3 - CHBASE] = p; \
        } \
    } \
    ++col; } while (0)
    EMIT(1.0f);                                   // bias
    #pragma unroll
    for (int i = 0; i < NFEAT; ++i) EMIT(xr[i]);  // degree 1
    #pragma unroll
    for (int i = 0; i < NFEAT; ++i)               // degree 2
        #pragma unroll
        for (int j = i; j < NFEAT; ++j) EMIT(xr[i] * xr[j]);
    #pragma unroll
    for (int i = 0; i < NFEAT; ++i)               // degree 3 (x_i*x_j reused via CSE)
        #pragma unroll
        for (int j = i; j < NFEAT; ++j)
            #pragma unroll
            for (int k = j; k < NFEAT; ++k) EMIT((xr[i] * xr[j]) * xr[k]);
#undef EMIT
    constexpr int rem = (REND - RBASE) & 3;       // ragged tail
    if constexpr (rem != 0) {
        #pragma unroll
        for (int e = 0; e < rem; ++e) ldsrow[REND - rem + e - CHBASE] = buf[e];
    }
}

// 8 ranges per chunk, chunk-local bases {0,40,...,280}, last range 43 cols.
#define CHUNK_DISPATCH(NAME, CB) \
__device__ __forceinline__ void NAME(int range, const float* xr, float* ldsrow) { \
    switch (range) { \
        case 0: compute_range<CB, CB +   0, CB +  40>(xr, ldsrow); break; \
        case 1: compute_range<CB, CB +  40, CB +  80>(xr, ldsrow); break; \
        case 2: compute_range<CB, CB +  80, CB + 120>(xr, ldsrow); break; \
        case 3: compute_range<CB, CB + 120, CB + 160>(xr, ldsrow); break; \
        case 4: compute_range<CB, CB + 160, CB + 200>(xr, ldsrow); break; \
        case 5: compute_range<CB, CB + 200, CB + 240>(xr, ldsrow); break; \
        case 6: compute_range<CB, CB + 240, CB + 280>(xr, ldsrow); break; \
        case 7: compute_range<CB, CB + 280, CB + 323>(xr, ldsrow); break; \
    } \
}
CHUNK_DISPATCH(compute_chunk0, 0)
CHUNK_DISPATCH(compute_chunk1, 323)
CHUNK_DISPATCH(compute_chunk2, 646)
#undef CHUNK_DISPATCH

// Copy the 32x323 chunk LDS -> out. Per-row segments are 1292B contiguous.
__device__ __forceinline__ void store_chunk(float* __restrict__ dst, int tid,
                                            const float* lds) {
    #pragma unroll 4
    for (int g = tid; g < PASS_ROWS * CHUNK; g += 256) {
        int r = g / CHUNK;              // constant divisor -> magic multiply
        int c = g - r * CHUNK;
        __builtin_nontemporal_store(lds[r * LSTRIDE + c], dst + (size_t)r * NCOLS + c);
    }
}

__global__ void __launch_bounds__(256, 3)
poly_chunk(const float* __restrict__ x, float* __restrict__ out) {
    __shared__ float lds[PASS_ROWS * LSTRIDE];   // 41,472 B -> 3 blocks/CU

    const int tid   = threadIdx.x;
    const int lrow  = tid & 31;                  // row within pass (32-lane bodies!)
    const int range = tid >> 5;                  // 0..7, uniform per half-wave
    const int bid   = blockIdx.x;
    const int rowgrp = bid / 3;                  // 0..2047
    const int chunk  = bid - rowgrp * 3;         // 0..2

    const int row0 = rowgrp * PASS_ROWS;
    const floatx4* xv = (const floatx4*)(x + (size_t)(row0 + lrow) * NFEAT);
    floatx4 a0 = xv[0], a1 = xv[1], a2 = xv[2], a3 = xv[3];
    float xr[NFEAT] = {a0[0],a0[1],a0[2],a0[3], a1[0],a1[1],a1[2],a1[3],
                       a2[0],a2[1],a2[2],a2[3], a3[0],a3[1],a3[2],a3[3]};

    float* ldsrow = &lds[lrow * LSTRIDE];
    if (chunk == 0)      compute_chunk0(range, xr, ldsrow);
    else if (chunk == 1) compute_chunk1(range, xr, ldsrow);
    else                 compute_chunk2(range, xr, ldsrow);

    __syncthreads();
    store_chunk(out + (size_t)row0 * NCOLS + chunk * CHUNK, tid, lds);
}

extern "C" void kernel_launch(void* const* d_in, const int* in_sizes, int n_in,
                              void* d_out, int out_size, void* d_ws, size_t ws_size,
                              hipStream_t stream) {
    const float* x = (const float*)d_in[0];
    float* out = (float*)d_out;
    // 2048 row-groups x 3 column chunks; short-lived blocks, 3 resident/CU.
    poly_chunk<<<6144, 256, 0, stream>>>(x, out);
}

// Round 9
// 102.504 us; speedup vs baseline: 1.1411x; 1.1411x over previous
//
#include <hip/hip_runtime.h>
#include <stdint.h>

#define NFEAT 16
#define NCOLS 969            // 1 bias + 16 deg1 + 136 deg2 + 816 deg3
#define NROWS 65536
#define LSTRIDE 972          // LDS row stride (dwords): mult of 4, /4 odd -> 4-way max on b128 writes
#define PASS_ROWS 32
#define PASSES_PER_BLOCK 8   // 256 blocks * 8 passes * 32 rows = 65536
#define NTHREADS 512

typedef float floatx4 __attribute__((ext_vector_type(4)));

// ---------------------------------------------------------------------------
// Static compute of cols [CBASE, CEND) of one row into LDS. All 969 columns
// emitted in sklearn/jax reference order (verified absmax 0.0 R1/R3-R8);
// out-of-range emits are compile-time dead. 32 active lanes per body.
// ---------------------------------------------------------------------------
template<int CBASE, int CEND>
__device__ __forceinline__ void compute_range(const float* xr, float* ldsrow) {
    float buf[4];
    int col = 0;
#define EMIT(P) do { \
    if (col >= CBASE && col < CEND) { \
        buf[(col - CBASE) & 3] = (P); \
        if (((col - CBASE) & 3) == 3) { \
            floatx4 p; p[0] = buf[0]; p[1] = buf[1]; p[2] = buf[2]; p[3] = buf[3]; \
            *(floatx4*)&ldsrow[col - 3] = p; /* CBASE%4==0 -> 16B-aligned */ \
        } \
    } \
    ++col; } while (0)
    EMIT(1.0f);                                   // bias
    #pragma unroll
    for (int i = 0; i < NFEAT; ++i) EMIT(xr[i]);  // degree 1
    #pragma unroll
    for (int i = 0; i < NFEAT; ++i)               // degree 2
        #pragma unroll
        for (int j = i; j < NFEAT; ++j) EMIT(xr[i] * xr[j]);
    #pragma unroll
    for (int i = 0; i < NFEAT; ++i)               // degree 3 (x_i*x_j reused via CSE)
        #pragma unroll
        for (int j = i; j < NFEAT; ++j)
            #pragma unroll
            for (int k = j; k < NFEAT; ++k) EMIT((xr[i] * xr[j]) * xr[k]);
#undef EMIT
    constexpr int rem = (CEND - CBASE) & 3;       // ragged tail (range 15 only)
    if constexpr (rem != 0) {
        #pragma unroll
        for (int e = 0; e < rem; ++e) ldsrow[CEND - rem + e] = buf[e];
    }
}

__device__ __forceinline__ void compute_dispatch(int range, const float* xr, float* ldsrow) {
    switch (range) {   // uniform per 32-lane group; 2 serial bodies per wave
        case  0: compute_range<  0,  60>(xr, ldsrow); break;
        case  1: compute_range< 60, 120>(xr, ldsrow); break;
        case  2: compute_range<120, 180>(xr, ldsrow); break;
        case  3: compute_range<180, 240>(xr, ldsrow); break;
        case  4: compute_range<240, 300>(xr, ldsrow); break;
        case  5: compute_range<300, 360>(xr, ldsrow); break;
        case  6: compute_range<360, 420>(xr, ldsrow); break;
        case  7: compute_range<420, 480>(xr, ldsrow); break;
        case  8: compute_range<480, 540>(xr, ldsrow); break;
        case  9: compute_range<540, 600>(xr, ldsrow); break;
        case 10: compute_range<600, 660>(xr, ldsrow); break;
        case 11: compute_range<660, 720>(xr, ldsrow); break;
        case 12: compute_range<720, 780>(xr, ldsrow); break;
        case 13: compute_range<780, 840>(xr, ldsrow); break;
        case 14: compute_range<840, 900>(xr, ldsrow); break;
        case 15: compute_range<900, 969>(xr, ldsrow); break;
    }
}

// Div-free store: per row, thread tid covers cols {tid, tid+512}. Fully
// unrolled (64 store insts), incremental addresses, no magic divide.
// LDS reads: consecutive tid -> consecutive c -> conflict-free.
__device__ __forceinline__ void store_pass(float* __restrict__ dst, int tid,
                                           const float* lds) {
    #pragma unroll
    for (int r = 0; r < PASS_ROWS; ++r) {
        const float* lrow = lds + r * LSTRIDE;
        float* drow = dst + (size_t)r * NCOLS;
        __builtin_nontemporal_store(lrow[tid], drow + tid);
        int c2 = tid + NTHREADS;
        if (c2 < NCOLS)   // tid < 457; predicated, cheap
            __builtin_nontemporal_store(lrow[c2], drow + c2);
    }
}

__global__ void __launch_bounds__(NTHREADS, 2)
poly_rows(const float* __restrict__ x, float* __restrict__ out) {
    __shared__ float lds[PASS_ROWS * LSTRIDE];   // 124,416 B -> 1 block/CU, 8 waves

    const int tid   = threadIdx.x;
    const int lrow  = tid & 31;                  // row within pass
    const int range = tid >> 5;                  // 0..15, uniform per 32-lane group

    float* ldsrow = &lds[lrow * LSTRIDE];
    const int base = blockIdx.x * (PASSES_PER_BLOCK * PASS_ROWS);

    // x-row for pass 0
    const floatx4* xv = (const floatx4*)(x + (size_t)(base + lrow) * NFEAT);
    floatx4 a0 = xv[0], a1 = xv[1], a2 = xv[2], a3 = xv[3];

    for (int p = 0; p < PASSES_PER_BLOCK; ++p) {
        float xr[NFEAT] = {a0[0],a0[1],a0[2],a0[3], a1[0],a1[1],a1[2],a1[3],
                           a2[0],a2[1],a2[2],a2[3], a3[0],a3[1],a3[2],a3[3]};
        compute_dispatch(range, xr, ldsrow);

        // prefetch next pass's x-row; vmcnt waited only at next use (after stores)
        if (p + 1 < PASSES_PER_BLOCK) {
            const floatx4* nv = (const floatx4*)
                (x + (size_t)(base + (p + 1) * PASS_ROWS + lrow) * NFEAT);
            a0 = nv[0]; a1 = nv[1]; a2 = nv[2]; a3 = nv[3];
        }

        // LDS-visibility barrier WITHOUT vmcnt(0) drain (raw s_barrier):
        // ds_writes must be visible -> lgkmcnt(0); outstanding global stores
        // of the previous pass may stay in flight across the barrier.
        asm volatile("s_waitcnt lgkmcnt(0)" ::: "memory");
        __builtin_amdgcn_s_barrier();

        store_pass(out + (size_t)(base + p * PASS_ROWS) * NCOLS, tid, lds);

        // Before next compute overwrites LDS: every wave's ds_reads completed
        // before its stores issued (data dep), so a raw barrier suffices.
        __builtin_amdgcn_s_barrier();
    }
}

extern "C" void kernel_launch(void* const* d_in, const int* in_sizes, int n_in,
                              void* d_out, int out_size, void* d_ws, size_t ws_size,
                              hipStream_t stream) {
    const float* x = (const float*)d_in[0];
    float* out = (float*)d_out;
    // 256 blocks = 1 per CU (LDS-capped), persistent, 8 passes of 32 rows.
    poly_rows<<<256, NTHREADS, 0, stream>>>(x, out);
}

// Round 10
// 54.790 us; speedup vs baseline: 2.1348x; 1.8708x over previous
//
#include <hip/hip_runtime.h>
#include <stdint.h>

#define NFEAT 16
#define NCOLS 969            // 1 bias + 16 deg1 + 136 deg2 + 816 deg3
#define NROWS 65536
#define LSTRIDE 972          // dwords per LDS row: mult of 4 (16B f4 writes), %32=12 (bank spread)
#define PASS_ROWS 32
#define TILE_ROWS 64
#define TILES_PER_BLOCK 4    // 256 blocks * 4 tiles * 64 rows = 65536
#define PASS_ELEMS (PASS_ROWS * NCOLS)   // 31008 dwords, flat-contiguous in out

typedef float floatx4 __attribute__((ext_vector_type(4)));

// ---------------------------------------------------------------------------
// Static compute of cols [CBASE, CEND) of one row into LDS. All 969 columns
// emitted in sklearn/jax reference order (verified absmax 0.0 in R1/R3-R9);
// out-of-range emits are compile-time dead. Zero decode, zero gathers.
// NOTE: no __launch_bounds__ VGPR cap — this body needs >256 VGPRs; caps
// caused the R7/R8/R9 spill regressions.
// ---------------------------------------------------------------------------
template<int CBASE, int CEND>
__device__ __forceinline__ void compute_range(const float* xr, float* ldsrow) {
    float buf[4];
    int col = 0;
#define EMIT(P) do { \
    if (col >= CBASE && col < CEND) { \
        buf[(col - CBASE) & 3] = (P); \
        if (((col - CBASE) & 3) == 3) { \
            floatx4 p; p[0] = buf[0]; p[1] = buf[1]; p[2] = buf[2]; p[3] = buf[3]; \
            *(floatx4*)&ldsrow[col - 3] = p; /* CBASE%4==0 -> col-3 is 16B-aligned */ \
        } \
    } \
    ++col; } while (0)
    EMIT(1.0f);                                   // bias
    #pragma unroll
    for (int i = 0; i < NFEAT; ++i) EMIT(xr[i]);  // degree 1
    #pragma unroll
    for (int i = 0; i < NFEAT; ++i)               // degree 2
        #pragma unroll
        for (int j = i; j < NFEAT; ++j) EMIT(xr[i] * xr[j]);
    #pragma unroll
    for (int i = 0; i < NFEAT; ++i)               // degree 3 (reuses x_i*x_j via CSE)
        #pragma unroll
        for (int j = i; j < NFEAT; ++j)
            #pragma unroll
            for (int k = j; k < NFEAT; ++k) EMIT((xr[i] * xr[j]) * xr[k]);
#undef EMIT
    constexpr int rem = (CEND - CBASE) & 3;       // ragged tail (only range 7: 1 elem)
    if constexpr (rem != 0) {
        #pragma unroll
        for (int e = 0; e < rem; ++e) ldsrow[CEND - rem + e] = buf[e];
    }
}

__device__ __forceinline__ void compute_dispatch(int range, const float* xr, float* ldsrow) {
    switch (range) {   // range is uniform per 32-lane half-wave -> 2-way wave divergence max
        case 0: compute_range<  0, 124>(xr, ldsrow); break;
        case 1: compute_range<124, 248>(xr, ldsrow); break;
        case 2: compute_range<248, 372>(xr, ldsrow); break;
        case 3: compute_range<372, 496>(xr, ldsrow); break;
        case 4: compute_range<496, 620>(xr, ldsrow); break;
        case 5: compute_range<620, 744>(xr, ldsrow); break;
        case 6: compute_range<744, 868>(xr, ldsrow); break;
        case 7: compute_range<868, 969>(xr, ldsrow); break;
    }
}

// Flat contiguous copy LDS -> out for one 32-row pass (31008 dwords).
// Wave stores are 256B contiguous; LDS reads stride-1 (conflict-free).
__device__ __forceinline__ void store_pass(float* __restrict__ out, int rowbase,
                                           int tid, const float* lds) {
    float* dst = out + (size_t)rowbase * NCOLS;
    #pragma unroll 4
    for (int g = tid; g < PASS_ELEMS; g += 256) {
        int r = g / NCOLS;              // constant divisor -> magic multiply
        int c = g - r * NCOLS;
        __builtin_nontemporal_store(lds[r * LSTRIDE + c], dst + g);
    }
}

// Raw barrier WITHOUT vmcnt(0) drain: LDS visibility needs only lgkmcnt(0);
// in-flight global stores have already captured their data (each store issued
// after its ds_read completed), so they may drain across the barrier while
// the next pass computes. This is the R6 -> R10 change: overlap store drain
// with next-pass compute instead of idling all waves at __syncthreads().
__device__ __forceinline__ void lds_barrier() {
    asm volatile("s_waitcnt lgkmcnt(0)" ::: "memory");
    __builtin_amdgcn_s_barrier();
}

__global__ void __launch_bounds__(256, 1)
poly_rows(const float* __restrict__ x, float* __restrict__ out) {
    __shared__ float lds[PASS_ROWS * LSTRIDE];   // 124,416 B -> 1 block/CU

    const int tid  = threadIdx.x;
    const int lane = tid & 63;
    const int half = lane >> 5;                  // 0/1: half-wave id
    const int lrow = lane & 31;                  // row within pass
    const int range = ((tid >> 6) << 1) + half;  // 0..7, uniform per half-wave
    float* ldsrow = &lds[lrow * LSTRIDE];

    for (int it = 0; it < TILES_PER_BLOCK; ++it) {
        const int row0 = (blockIdx.x * TILES_PER_BLOCK + it) * TILE_ROWS;

        // Each lane loads the two x-rows it computes with (pass A and pass B).
        const floatx4* xa = (const floatx4*)(x + (size_t)(row0 + lrow) * NFEAT);
        const floatx4* xb = (const floatx4*)(x + (size_t)(row0 + 32 + lrow) * NFEAT);
        floatx4 a0 = xa[0], a1 = xa[1], a2 = xa[2], a3 = xa[3];
        floatx4 b0 = xb[0], b1 = xb[1], b2 = xb[2], b3 = xb[3];
        float xrA[NFEAT] = {a0[0],a0[1],a0[2],a0[3], a1[0],a1[1],a1[2],a1[3],
                            a2[0],a2[1],a2[2],a2[3], a3[0],a3[1],a3[2],a3[3]};
        float xrB[NFEAT] = {b0[0],b0[1],b0[2],b0[3], b1[0],b1[1],b1[2],b1[3],
                            b2[0],b2[1],b2[2],b2[3], b3[0],b3[1],b3[2],b3[3]};

        // ---- pass A: rows row0..row0+31 ----
        compute_dispatch(range, xrA, ldsrow);
        lds_barrier();
        store_pass(out, row0, tid, lds);
        lds_barrier();
        // ---- pass B: rows row0+32..row0+63 ----
        compute_dispatch(range, xrB, ldsrow);
        lds_barrier();
        store_pass(out, row0 + 32, tid, lds);
        lds_barrier();
    }
}

extern "C" void kernel_launch(void* const* d_in, const int* in_sizes, int n_in,
                              void* d_out, int out_size, void* d_ws, size_t ws_size,
                              hipStream_t stream) {
    const float* x = (const float*)d_in[0];
    float* out = (float*)d_out;
    // 256 blocks (1 per CU, LDS-capped), 4 tiles of 64 rows each.
    poly_rows<<<256, 256, 0, stream>>>(x, out);
}

// Round 11
// 46.823 us; speedup vs baseline: 2.4981x; 1.1702x over previous
//
#include <hip/hip_runtime.h>
#include <stdint.h>

#define NFEAT 16
#define NCOLS 969            // 1 bias + 16 deg1 + 136 deg2 + 816 deg3
#define NROWS 65536
#define LSTRIDE 969          // PACKED: LDS tile is an exact image of the output pass
#define PASS_ROWS 32
#define TILE_ROWS 64
#define TILES_PER_BLOCK 4    // 256 blocks * 4 tiles * 64 rows = 65536
#define PASS_ELEMS (PASS_ROWS * NCOLS)   // 31008 dwords, flat-contiguous in out

typedef float floatx4 __attribute__((ext_vector_type(4)));

// ---------------------------------------------------------------------------
// Static compute of cols [CBASE, CEND) of one row into packed LDS. All 969
// columns emitted in sklearn/jax reference order (verified absmax 0.0
// R1/R3-R10); out-of-range emits are compile-time dead. Scalar ds_write_b32:
// packed stride 969 (odd) forbids b128, but (9*lrow + col) mod 32 covers all
// 32 banks (gcd(9,32)=1) -> conflict-free; compiler merges into ds_write2_b32.
// NOTE: no __launch_bounds__ VGPR cap (R7/R8/R9 spill lesson).
// ---------------------------------------------------------------------------
template<int CBASE, int CEND>
__device__ __forceinline__ void compute_range(const float* xr, float* ldsrow) {
    int col = 0;
#define EMIT(P) do { if (col >= CBASE && col < CEND) ldsrow[col] = (P); ++col; } while (0)
    EMIT(1.0f);                                   // bias
    #pragma unroll
    for (int i = 0; i < NFEAT; ++i) EMIT(xr[i]);  // degree 1
    #pragma unroll
    for (int i = 0; i < NFEAT; ++i)               // degree 2
        #pragma unroll
        for (int j = i; j < NFEAT; ++j) EMIT(xr[i] * xr[j]);
    #pragma unroll
    for (int i = 0; i < NFEAT; ++i)               // degree 3 (reuses x_i*x_j via CSE)
        #pragma unroll
        for (int j = i; j < NFEAT; ++j)
            #pragma unroll
            for (int k = j; k < NFEAT; ++k) EMIT((xr[i] * xr[j]) * xr[k]);
#undef EMIT
}

__device__ __forceinline__ void compute_dispatch(int range, const float* xr, float* ldsrow) {
    switch (range) {   // range is uniform per 32-lane half-wave -> 2-way wave divergence max
        case 0: compute_range<  0, 124>(xr, ldsrow); break;
        case 1: compute_range<124, 248>(xr, ldsrow); break;
        case 2: compute_range<248, 372>(xr, ldsrow); break;
        case 3: compute_range<372, 496>(xr, ldsrow); break;
        case 4: compute_range<496, 620>(xr, ldsrow); break;
        case 5: compute_range<620, 744>(xr, ldsrow); break;
        case 6: compute_range<744, 868>(xr, ldsrow); break;
        case 7: compute_range<868, 969>(xr, ldsrow); break;
    }
}

// Store phase = pure flat copy of the packed LDS image (fill-kernel shape):
// ds_read_b128 + global_store_dwordx4, both 16B-aligned (pass base is a
// 31008-dword multiple; 31008 % 4 == 0). 30-31 iterations/thread, no divide.
__device__ __forceinline__ void store_pass(float* __restrict__ out, int rowbase,
                                           int tid, const float* lds) {
    floatx4* dst4 = (floatx4*)(out + (size_t)rowbase * NCOLS);
    const floatx4* lds4 = (const floatx4*)lds;
    #pragma unroll 4
    for (int g4 = tid; g4 < PASS_ELEMS / 4; g4 += 256)   // 7752 groups
        dst4[g4] = lds4[g4];
}

// Raw barrier WITHOUT vmcnt(0) drain: LDS visibility needs only lgkmcnt(0);
// in-flight global stores already captured their data registers, so they may
// drain across the barrier while the next pass computes.
__device__ __forceinline__ void lds_barrier() {
    asm volatile("s_waitcnt lgkmcnt(0)" ::: "memory");
    __builtin_amdgcn_s_barrier();
}

__global__ void __launch_bounds__(256, 1)
poly_rows(const float* __restrict__ x, float* __restrict__ out) {
    __shared__ __align__(16) float lds[PASS_ROWS * LSTRIDE];   // 124,032 B -> 1 block/CU

    const int tid  = threadIdx.x;
    const int lane = tid & 63;
    const int half = lane >> 5;                  // 0/1: half-wave id
    const int lrow = lane & 31;                  // row within pass
    const int range = ((tid >> 6) << 1) + half;  // 0..7, uniform per half-wave
    float* ldsrow = &lds[lrow * LSTRIDE];

    for (int it = 0; it < TILES_PER_BLOCK; ++it) {
        const int row0 = (blockIdx.x * TILES_PER_BLOCK + it) * TILE_ROWS;

        // Each lane loads the two x-rows it computes with (pass A and pass B).
        const floatx4* xa = (const floatx4*)(x + (size_t)(row0 + lrow) * NFEAT);
        const floatx4* xb = (const floatx4*)(x + (size_t)(row0 + 32 + lrow) * NFEAT);
        floatx4 a0 = xa[0], a1 = xa[1], a2 = xa[2], a3 = xa[3];
        floatx4 b0 = xb[0], b1 = xb[1], b2 = xb[2], b3 = xb[3];
        float xrA[NFEAT] = {a0[0],a0[1],a0[2],a0[3], a1[0],a1[1],a1[2],a1[3],
                            a2[0],a2[1],a2[2],a2[3], a3[0],a3[1],a3[2],a3[3]};
        float xrB[NFEAT] = {b0[0],b0[1],b0[2],b0[3], b1[0],b1[1],b1[2],b1[3],
                            b2[0],b2[1],b2[2],b2[3], b3[0],b3[1],b3[2],b3[3]};

        // ---- pass A: rows row0..row0+31 ----
        compute_dispatch(range, xrA, ldsrow);
        lds_barrier();
        store_pass(out, row0, tid, lds);
        lds_barrier();
        // ---- pass B: rows row0+32..row0+63 ----
        compute_dispatch(range, xrB, ldsrow);
        lds_barrier();
        store_pass(out, row0 + 32, tid, lds);
        lds_barrier();
    }
}

extern "C" void kernel_launch(void* const* d_in, const int* in_sizes, int n_in,
                              void* d_out, int out_size, void* d_ws, size_t ws_size,
                              hipStream_t stream) {
    const float* x = (const float*)d_in[0];
    float* out = (float*)d_out;
    // 256 blocks (1 per CU, LDS-capped), 4 tiles of 64 rows each.
    poly_rows<<<256, 256, 0, stream>>>(x, out);
}